// Round 17
// baseline (194.419 us; speedup 1.0000x reference)
//
#include <hip/hip_runtime.h>
#include <stdint.h>

#define NBATCH 16
#define NANCH  9
#define NHGT   128
#define NWID   256
#define NHW    (NHGT * NWID)       // 32768
#define NTOT   (NHW * NANCH)       // 294912
#define PRE    6000
#define POST   300
#define CAPN   8192
#define BINS   8192
#define BIN_SHIFT 19
#define NWORDS 94                  // ceil(6000/64)
#define NWSTRIDE 96                // padded row stride (words) -> 768 B, 16B-aligned
#define RROWS  512                 // suppression-matrix rows (exact fallback beyond)
#define NGROUPS (RROWS / 8)        // 64 groups of 8 rows
#define JHALF  3072                // j-split point for k_iou (words 0..47 | 48..93)
#define JREM   (PRE - JHALF)       // 2928

// exact replacement for (div_rn(inter,uni) > 0.7f):  (double)inter >= (double)uni * M
#define MIDP 0x1.6666668p-1

__device__ __constant__ float c_AW[NANCH] = {184.f,368.f,736.f,128.f,256.f,512.f,88.f,176.f,352.f};
__device__ __constant__ float c_AH[NANCH] = {96.f,192.f,384.f,128.f,256.f,512.f,176.f,352.f,704.f};

__device__ __forceinline__ uint32_t f2key(float f) {
    uint32_t u = __float_as_uint(f);
    return (u & 0x80000000u) ? ~u : (u | 0x80000000u);
}

__device__ __forceinline__ bool iou_sup(const float4 bi, float areaI, const float4 bj, float areaJ) {
    float xx1 = fmaxf(bi.x, bj.x);
    float yy1 = fmaxf(bi.y, bj.y);
    float xx2 = fminf(bi.z, bj.z);
    float yy2 = fminf(bi.w, bj.w);
    float iw = fmaxf(__fadd_rn(__fsub_rn(xx2, xx1), 1.f), 0.f);
    float ih = fmaxf(__fadd_rn(__fsub_rn(yy2, yy1), 1.f), 0.f);
    float inter = __fmul_rn(iw, ih);
    float uni = __fsub_rn(__fadd_rn(areaI, areaJ), inter);
    return ((double)inter >= (double)uni * MIDP);
}

__device__ __forceinline__ bool decode_clip(float dx, float dy, float dw, float dh,
                                            float aw, float ah, float acx, float acy,
                                            float& x1, float& y1, float& x2, float& y2) {
    float pcx = __fadd_rn(__fmul_rn(dx, aw), acx);
    float pcy = __fadd_rn(__fmul_rn(dy, ah), acy);
    float pw  = __fmul_rn(expf(dw), aw);
    float ph  = __fmul_rn(expf(dh), ah);
    float hx  = __fmul_rn(0.5f, pw);
    float hy  = __fmul_rn(0.5f, ph);
    x1 = __fsub_rn(pcx, hx);
    y1 = __fsub_rn(pcy, hy);
    x2 = __fadd_rn(pcx, hx);
    y2 = __fadd_rn(pcy, hy);
    x1 = fminf(fmaxf(x1, 0.f), 4095.f);
    x2 = fminf(fmaxf(x2, 0.f), 4095.f);
    y1 = fminf(fmaxf(y1, 0.f), 2047.f);
    y2 = fminf(fmaxf(y2, 0.f), 2047.f);
    float wpl = __fadd_rn(__fsub_rn(x2, x1), 1.f);
    float hpl = __fadd_rn(__fsub_rn(y2, y1), 1.f);
    return (wpl >= 16.f) && (hpl >= 16.f);
}

// ---------------- K0: zero ghist + cnt + thr (replaces slow runtime fill) ----------------
__global__ __launch_bounds__(256) void k_zero(uint4* __restrict__ ghist4,
                                              uint32_t* __restrict__ cntthr) {
    int g = blockIdx.x * 256 + threadIdx.x;
    if (blockIdx.x < 128) {
        ghist4[g] = make_uint4(0, 0, 0, 0);      // 128*256*16 = 524288 B
    } else {
        if (threadIdx.x < 32) cntthr[threadIdx.x] = 0;   // cnt(64B) + thr(64B)
    }
}

// ---------------- K1: LDS histogram (1024 blocks, float2 loads) + key array ----------------
__global__ __launch_bounds__(256) void k_hist(const float* __restrict__ lab,
                                              const float* __restrict__ reg,
                                              uint32_t* __restrict__ ghist,
                                              uint32_t* __restrict__ keys) {
    __shared__ uint32_t hist[BINS];
    for (int i = threadIdx.x; i < BINS; i += 256) hist[i] = 0;
    __syncthreads();
    int b = blockIdx.x >> 6, sub = blockIdx.x & 63;
    int hw = (sub << 9) | (threadIdx.x << 1);
    int h = hw >> 8, w = hw & 255;
    const float* lb = lab + (size_t)b * 18 * NHW + hw;
    const float* rb = reg + (size_t)b * 36 * NHW + hw;
    uint32_t* kb = keys + (size_t)b * NANCH * NHW + hw;
    float acx0 = (float)(w * 16) + 7.5f;
    float acx1 = acx0 + 16.0f;
    float acy  = (float)(h * 16) + 7.5f;
#pragma unroll
    for (int a = 0; a < NANCH; ++a) {
        float2 s  = *(const float2*)&lb[(2 * a + 1) * NHW];
        float2 dx = *(const float2*)&rb[(4 * a + 0) * NHW];
        float2 dy = *(const float2*)&rb[(4 * a + 1) * NHW];
        float2 dwv = *(const float2*)&rb[(4 * a + 2) * NHW];
        float2 dhv = *(const float2*)&rb[(4 * a + 3) * NHW];
        float x1, y1, x2, y2;
        bool k0 = decode_clip(dx.x, dy.x, dwv.x, dhv.x, c_AW[a], c_AH[a], acx0, acy, x1, y1, x2, y2);
        bool k1 = decode_clip(dx.y, dy.y, dwv.y, dhv.y, c_AW[a], c_AH[a], acx1, acy, x1, y1, x2, y2);
        uint32_t key0 = f2key(k0 ? s.x : -1e30f);
        uint32_t key1 = f2key(k1 ? s.y : -1e30f);
        *(uint2*)&kb[a * NHW] = make_uint2(key0, key1);
        atomicAdd(&hist[key0 >> BIN_SHIFT], 1u);
        atomicAdd(&hist[key1 >> BIN_SHIFT], 1u);
    }
    __syncthreads();
    uint32_t* gh = ghist + ((size_t)b << 13);
    for (int i = threadIdx.x; i < BINS; i += 256) {
        uint32_t c = hist[i];
        if (c) atomicAdd(&gh[i], c);
    }
}

// ---------------- K2: find threshold bin (cumulative from top >= PRE) ----------------
__global__ __launch_bounds__(256) void k_thresh(const uint32_t* __restrict__ ghist,
                                                uint32_t* __restrict__ thresh) {
    __shared__ uint32_t part[256];
    int b = blockIdx.x;
    const uint32_t* gh = ghist + ((size_t)b << 13);
    uint32_t p = 0;
    int base = threadIdx.x * 32;
    for (int k = 0; k < 32; ++k) p += gh[base + k];
    part[threadIdx.x] = p;
    __syncthreads();
    if (threadIdx.x == 0) {
        uint32_t cum = 0;
        int tb = 0;
        for (int c = 255; c >= 0; --c) {
            if (cum + part[c] >= (uint32_t)PRE) {
                for (int i = 31; i >= 0; --i) {
                    cum += gh[c * 32 + i];
                    if (cum >= (uint32_t)PRE) { tb = c * 32 + i; break; }
                }
                break;
            }
            cum += part[c];
        }
        thresh[b] = (uint32_t)tb << BIN_SHIFT;
    }
}

// ---------------- K3: compact from key array; LDS staging, 1 atomic/block ----------------
__global__ __launch_bounds__(256) void k_compact(const uint32_t* __restrict__ keys,
                                                 const uint32_t* __restrict__ thresh,
                                                 uint32_t* __restrict__ cnt,
                                                 uint64_t* __restrict__ cand) {
    __shared__ uint64_t stage[2304];
    __shared__ uint32_t sCount;
    __shared__ uint32_t sBase;
    if (threadIdx.x == 0) sCount = 0;
    __syncthreads();
    int bid = blockIdx.x;
    int b = bid >> 7;
    int hw = ((bid & 127) << 8) | threadIdx.x;
    int lane = threadIdx.x & 63;
    const uint32_t* kb = keys + (size_t)b * NANCH * NHW + hw;
    uint32_t th = thresh[b];
#pragma unroll
    for (int a = 0; a < NANCH; ++a) {
        uint32_t key = kb[a * NHW];
        bool valid = (key >= th);
        uint64_t mask = __ballot(valid);
        if (mask) {
            int leader = __ffsll((unsigned long long)mask) - 1;
            uint32_t wb = 0;
            if (lane == leader) wb = atomicAdd(&sCount, (uint32_t)__popcll(mask));
            wb = (uint32_t)__shfl((int)wb, leader);
            if (valid) {
                int rank = __popcll(mask & ((1ull << lane) - 1ull));
                uint32_t n = (uint32_t)(hw * NANCH + a);
                stage[wb + rank] = ((uint64_t)key << 32) | (uint32_t)(~n);
            }
        }
    }
    __syncthreads();
    if (threadIdx.x == 0) sBase = atomicAdd(&cnt[b], sCount);
    __syncthreads();
    uint32_t total = sCount, base = sBase;
    for (uint32_t i = threadIdx.x; i < total; i += 256) {
        uint32_t pos = base + i;
        if (pos < (uint32_t)CAPN) cand[(size_t)b * CAPN + pos] = stage[i];
    }
}

// ---------------- K4a: sort each 1024-chunk DESCENDING (local bitonic) ----------------
__global__ __launch_bounds__(512) void k_sortA(const uint32_t* __restrict__ cnt,
                                               uint64_t* __restrict__ cand) {
    __shared__ uint64_t sm[1024];            // 8 KiB
    int b = blockIdx.x >> 3, c = blockIdx.x & 7;
    uint32_t C = cnt[b];
    if (C > (uint32_t)CAPN) C = CAPN;
    uint64_t* cb = cand + (size_t)b * CAPN;
    int base = c << 10;
    for (int li = threadIdx.x; li < 1024; li += 512) {
        int gi = base + li;
        sm[li] = (gi < (int)C) ? cb[gi] : 0ull;
    }
    __syncthreads();
    for (int k = 2; k <= 1024; k <<= 1) {
        for (int j = k >> 1; j > 0; j >>= 1) {
            for (int li = threadIdx.x; li < 1024; li += 512) {
                int lxj = li ^ j;
                if (lxj > li) {
                    uint64_t va = sm[li], vb = sm[lxj];
                    bool up = ((li & k) == 0);
                    bool sw = up ? (va < vb) : (va > vb);
                    if (sw) { sm[li] = vb; sm[lxj] = va; }
                }
            }
            __syncthreads();
        }
    }
    for (int li = threadIdx.x; li < 1024; li += 512) cb[base + li] = sm[li];
}

// ---------------- K4b: pairwise merge-path (desc runs of length R=1<<Rlog) --------------
__global__ __launch_bounds__(256) void k_merge(const uint64_t* __restrict__ src,
                                               uint64_t* __restrict__ dst,
                                               int Rlog) {
    int g = blockIdx.x * 256 + threadIdx.x;
    if (g >= NBATCH * CAPN) return;
    int b = g >> 13;
    int p = g & (CAPN - 1);
    int R = 1 << Rlog;
    int pair = p >> (Rlog + 1);
    int q = p & ((R << 1) - 1);
    const uint64_t* A = src + (size_t)b * CAPN + ((size_t)(pair << 1) << Rlog);
    const uint64_t* B = A + R;
    int lo = (q > R) ? (q - R) : 0;
    int hi = (q < R) ? q : R;
    while (lo < hi) {
        int mid = (lo + hi) >> 1;
        if (A[mid] > B[q - mid - 1]) lo = mid + 1; else hi = mid;
    }
    int i = lo, j = q - lo;
    uint64_t aV = (i < R) ? A[i] : 0ull;
    uint64_t bV = (j < R) ? B[j] : 0ull;
    dst[(size_t)b * CAPN + p] = (aV > bV) ? aV : bV;
}

// ---------------- K4c: merge-path top-PRE over two DESC 4096-runs + gather/decode -------
__global__ __launch_bounds__(256) void k_mergegather(const uint64_t* __restrict__ cand,
                                                     const float* __restrict__ lab,
                                                     const float* __restrict__ reg,
                                                     float4* __restrict__ boxes,
                                                     float* __restrict__ scores) {
    int g = blockIdx.x * 256 + threadIdx.x;
    if (g >= NBATCH * PRE) return;
    int b = g / PRE, p = g - b * PRE;
    const uint64_t* A = cand + (size_t)b * CAPN;
    const uint64_t* B = A + 4096;
    int lo = (p > 4096) ? (p - 4096) : 0;
    int hi = (p < 4096) ? p : 4096;
    while (lo < hi) {
        int mid = (lo + hi) >> 1;
        if (A[mid] > B[p - mid - 1]) lo = mid + 1; else hi = mid;
    }
    int i = lo, j = p - lo;
    uint64_t aV = (i < 4096) ? A[i] : 0ull;
    uint64_t bV = (j < 4096) ? B[j] : 0ull;
    uint64_t v = (aV > bV) ? aV : bV;
    uint32_t n = ~(uint32_t)(v & 0xFFFFFFFFull);
    if (n >= (uint32_t)NTOT) n = 0;
    int a = (int)(n % NANCH);
    int hw = (int)(n / NANCH);
    int w = hw & 255, h = hw >> 8;
    const float* lb0 = lab + (size_t)b * 18 * NHW;
    const float* rb0 = reg + (size_t)b * 36 * NHW;
    float s  = lb0[(2 * a + 1) * NHW + hw];
    float dx = rb0[(4 * a + 0) * NHW + hw];
    float dy = rb0[(4 * a + 1) * NHW + hw];
    float dwv = rb0[(4 * a + 2) * NHW + hw];
    float dhv = rb0[(4 * a + 3) * NHW + hw];
    float acx = (float)(w * 16) + 7.5f;
    float acy = (float)(h * 16) + 7.5f;
    float x1, y1, x2, y2;
    decode_clip(dx, dy, dwv, dhv, c_AW[a], c_AH[a], acx, acy, x1, y1, x2, y2);
    boxes[b * PRE + p] = make_float4(x1, y1, x2, y2);
    scores[b * PRE + p] = s;
}

// ---------------- K6a: suppression bit-matrix, j-split halves, 2 rows per pass ----------
__global__ __launch_bounds__(512) void k_iou(const float4* __restrict__ boxes,
                                             uint64_t* __restrict__ supp) {
    __shared__ float4 lb[JHALF];
    __shared__ float  la[JHALF];
    int half = blockIdx.x & 1;
    int rblk = (blockIdx.x >> 1) & 15;
    int b    = blockIdx.x >> 5;
    const float4* bb = boxes + b * PRE;
    int jbase  = half ? JHALF : 0;
    int jcount = half ? JREM : JHALF;
    for (int i = threadIdx.x; i < jcount; i += 512) {
        float4 v = bb[jbase + i];
        lb[i] = v;
        la[i] = __fmul_rn(__fadd_rn(__fsub_rn(v.z, v.x), 1.f),
                          __fadd_rn(__fsub_rn(v.w, v.y), 1.f));
    }
    __syncthreads();
    int wave = threadIdx.x >> 6, lane = threadIdx.x & 63;
    int wlo = half ? 48 : 0;
    int whi = half ? NWORDS : 48;
#pragma unroll 1
    for (int m = 0; m < 2; ++m) {
        int r0 = rblk + 16 * wave + 128 * m;     // < 256
        int r1 = r0 + 256;                       // < 512
        float4 bi0 = bb[r0];
        float4 bi1 = bb[r1];
        float a0 = __fmul_rn(__fadd_rn(__fsub_rn(bi0.z, bi0.x), 1.f),
                             __fadd_rn(__fsub_rn(bi0.w, bi0.y), 1.f));
        float a1 = __fmul_rn(__fadd_rn(__fsub_rn(bi1.z, bi1.x), 1.f),
                             __fadd_rn(__fsub_rn(bi1.w, bi1.y), 1.f));
        uint64_t keep0 = 0ull, keep1 = 0ull;
        int w0 = r0 >> 6;                        // <= 3
        int wstart = (wlo > w0) ? wlo : w0;
        for (int w = wstart; w < whi; ++w) {
            int j = (w << 6) | lane;
            bool s0 = false, s1 = false;
            if (j < PRE) {
                int idx = j - jbase;
                float4 bj = lb[idx];
                float aj = la[idx];
                s0 = iou_sup(bi0, a0, bj, aj);
                s1 = iou_sup(bi1, a1, bj, aj);
            }
            uint64_t m0 = __ballot(s0);
            uint64_t m1 = __ballot(s1);
            if (lane == w - wlo) { keep0 = m0; keep1 = m1; }
        }
        uint64_t* sr0 = supp + ((size_t)b * RROWS + r0) * NWSTRIDE;
        uint64_t* sr1 = supp + ((size_t)b * RROWS + r1) * NWSTRIDE;
        if (half == 0) {
            if (lane < 48) { sr0[lane] = keep0; sr1[lane] = keep1; }
        } else {
            if (lane < 48) {
                sr0[48 + lane] = (lane < 46) ? keep0 : 0ull;
                sr1[48 + lane] = (lane < 46) ? keep1 : 0ull;
            }
        }
    }
}

// ---------------- K6b: sequential walk; 6-buffer pinned prefetch; UNIFORM loads ----------
#define ISSUE(BUF, GRP) do {                                                               \
    int _g = (GRP); if (_g > NGROUPS - 1) _g = NGROUPS - 1;                                \
    int _jb = _g << 3;                                                                     \
    const ulonglong2* _p = (const ulonglong2*)(sbase + (size_t)_jb * NWSTRIDE) + lclamp;   \
    BUF##0 = _p[0];   BUF##1 = _p[48];  BUF##2 = _p[96];  BUF##3 = _p[144];                \
    BUF##4 = _p[192]; BUF##5 = _p[240]; BUF##6 = _p[288]; BUF##7 = _p[336];                \
    __builtin_amdgcn_sched_barrier(0);  /* pin: loads stay issued HERE, not sunk */        \
} while (0)

#define ROWP(RD, JB, R) {                                                                  \
    if (((curw >> (((JB) & 63) + (R))) & 1ull) != 0ull) {                                  \
        if (lane == 0) idxb[t] = (uint32_t)((JB) + (R));                                   \
        v0 &= ~RD.x; v1 &= ~RD.y;                                                          \
        int _w = ((JB) + (R)) >> 6;                                                        \
        uint64_t _sw = (uint64_t)__shfl((long long)((_w & 1) ? RD.y : RD.x), _w >> 1);     \
        curw &= ~_sw;                                                                      \
        ++t;                                                                               \
        if (t >= POST) goto walk_done;                                                     \
    }                                                                                      \
}

#define PROC(BUF, GRP) do {                                                                \
    int _jb2 = (GRP) << 3;                                                                 \
    if ((_jb2 & 63) == 0) {                                                                \
        int _wi = _jb2 >> 6;                                                               \
        uint64_t _c0 = (uint64_t)__shfl((long long)v0, _wi >> 1);                          \
        uint64_t _c1 = (uint64_t)__shfl((long long)v1, _wi >> 1);                          \
        curw = (_wi & 1) ? _c1 : _c0;                                                      \
    }                                                                                      \
    ROWP(BUF##0, _jb2, 0); ROWP(BUF##1, _jb2, 1); ROWP(BUF##2, _jb2, 2); ROWP(BUF##3, _jb2, 3); \
    ROWP(BUF##4, _jb2, 4); ROWP(BUF##5, _jb2, 5); ROWP(BUF##6, _jb2, 6); ROWP(BUF##7, _jb2, 7); \
} while (0)

__global__ __launch_bounds__(64, 1) void k_walk(const uint64_t* __restrict__ supp,
                                                uint32_t* __restrict__ flags,
                                                uint32_t* __restrict__ tsave,
                                                uint64_t* __restrict__ aliveSv,
                                                uint32_t* __restrict__ idxAll) {
    int b = blockIdx.x;
    int lane = threadIdx.x;
    int lclamp = (lane < 48) ? lane : 47;
    uint32_t* idxb = idxAll + b * POST;
    const uint64_t* sbase = supp + (size_t)b * RROWS * NWSTRIDE;
    uint64_t v0, v1;
    if (lane < 46)       { v0 = ~0ull; v1 = ~0ull; }
    else if (lane == 46) { v0 = ~0ull; v1 = (1ull << 48) - 1ull; }
    else                 { v0 = 0ull;  v1 = 0ull; }
    uint64_t curw = 0;
    int t = 0;
    int flag = 0;
    ulonglong2 A0,A1,A2,A3,A4,A5,A6,A7;
    ulonglong2 B0,B1,B2,B3,B4,B5,B6,B7;
    ulonglong2 C0,C1,C2,C3,C4,C5,C6,C7;
    ulonglong2 D0,D1,D2,D3,D4,D5,D6,D7;
    ulonglong2 E0,E1,E2,E3,E4,E5,E6,E7;
    ulonglong2 F0,F1,F2,F3,F4,F5,F6,F7;
    ISSUE(A, 0); ISSUE(B, 1); ISSUE(C, 2); ISSUE(D, 3); ISSUE(E, 4); ISSUE(F, 5);
    // NGROUPS = 64 = 10*6 + 4: main loop covers groups 0..59, tail covers 60..63.
    for (int g = 0; g < NGROUPS - 4; g += 6) {
        PROC(A, g);     ISSUE(A, g + 6);
        PROC(B, g + 1); ISSUE(B, g + 7);
        PROC(C, g + 2); ISSUE(C, g + 8);
        PROC(D, g + 3); ISSUE(D, g + 9);
        PROC(E, g + 4); ISSUE(E, g + 10);
        PROC(F, g + 5); ISSUE(F, g + 11);
    }
    PROC(A, NGROUPS - 4); PROC(B, NGROUPS - 3); PROC(C, NGROUPS - 2); PROC(D, NGROUPS - 1);
    {
        unsigned long long anyAlive = __ballot((v0 | v1) != 0ull);
        if (anyAlive == 0ull) {
            if (lane == 0) for (int tt = t; tt < POST; ++tt) idxb[tt] = 0u;
        } else {
            if (2 * lane < NWORDS)     aliveSv[b * NWORDS + 2 * lane] = v0;
            if (2 * lane + 1 < NWORDS) aliveSv[b * NWORDS + 2 * lane + 1] = v1;
            if (lane == 0) tsave[b] = (uint32_t)t;
            flag = 1;
        }
    }
walk_done:
    if (lane == 0) flags[b] = (uint32_t)flag;
}

// ---------------- K6c: rare exact fallback; records indices; early-exit flag==0 ----------
__global__ __launch_bounds__(512) void k_resume(const float4* __restrict__ boxes,
                                                const uint32_t* __restrict__ flags,
                                                const uint32_t* __restrict__ tsave,
                                                const uint64_t* __restrict__ aliveSv,
                                                uint32_t* __restrict__ idxAll) {
    int b = blockIdx.x;
    if (flags[b] == 0) return;
    __shared__ uint64_t alive[NWORDS];
    __shared__ uint32_t sCur;
    int tid = threadIdx.x;
    const float4* bb = boxes + b * PRE;
    uint32_t* idxb = idxAll + b * POST;
    if (tid < NWORDS) alive[tid] = aliveSv[b * NWORDS + tid];
    __syncthreads();
    int t0 = (int)tsave[b];
    for (int t = t0; t < POST; ++t) {
        if (tid == 0) sCur = 0xFFFFFFFFu;
        __syncthreads();
        if (tid < NWORDS) {
            uint64_t wd = alive[tid];
            if (wd) atomicMin(&sCur, (uint32_t)(tid * 64 + (__ffsll((unsigned long long)wd) - 1)));
        }
        __syncthreads();
        uint32_t cur = sCur;
        uint32_t e = (cur < (uint32_t)PRE) ? cur : 0u;
        if (tid == 0) {
            idxb[t] = e;
            if (cur < (uint32_t)PRE)
                atomicAnd(&alive[cur >> 6], ~(1ull << (cur & 63)));
        }
        if (cur < (uint32_t)PRE) {
            float4 bc = bb[e];
            float areaC = __fmul_rn(__fadd_rn(__fsub_rn(bc.z, bc.x), 1.f),
                                    __fadd_rn(__fsub_rn(bc.w, bc.y), 1.f));
            for (uint32_t j = cur + 1 + tid; j < (uint32_t)PRE; j += 512) {
                uint64_t wd = alive[j >> 6];
                if ((wd >> (j & 63)) & 1ull) {
                    float4 bj = bb[j];
                    float areaJ = __fmul_rn(__fadd_rn(__fsub_rn(bj.z, bj.x), 1.f),
                                            __fadd_rn(__fsub_rn(bj.w, bj.y), 1.f));
                    if (iou_sup(bc, areaC, bj, areaJ))
                        atomicAnd(&alive[j >> 6], ~(1ull << (j & 63)));
                }
            }
        }
        __syncthreads();
    }
}

// ---------------- K7: gather emitted indices -> output boxes + scores ----------------
__global__ __launch_bounds__(256) void k_out(const float4* __restrict__ boxes,
                                             const float* __restrict__ scores,
                                             const uint32_t* __restrict__ idxAll,
                                             float* __restrict__ out) {
    int g = blockIdx.x * 256 + threadIdx.x;
    if (g >= NBATCH * POST) return;
    int b = g / POST;
    uint32_t i = idxAll[g];
    if (i >= (uint32_t)PRE) i = 0;
    float4 bc = boxes[b * PRE + i];
    size_t ob = (size_t)g * 4;
    out[ob + 0] = bc.x; out[ob + 1] = bc.y;
    out[ob + 2] = bc.z; out[ob + 3] = bc.w;
    out[(size_t)NBATCH * POST * 4 + g] = scores[b * PRE + i];
}

extern "C" void kernel_launch(void* const* d_in, const int* in_sizes, int n_in,
                              void* d_out, int out_size, void* d_ws, size_t ws_size,
                              hipStream_t stream) {
    (void)in_sizes; (void)n_in; (void)out_size; (void)ws_size;
    const float* lab = (const float*)d_in[0];
    const float* reg = (const float*)d_in[1];
    float* out = (float*)d_out;
    char* ws = (char*)d_ws;

    // workspace layout (bytes)
    uint32_t* ghist  = (uint32_t*)(ws + 0);          // 16*8192*4 = 524288
    uint32_t* cnt    = (uint32_t*)(ws + 524288);     // 64
    uint32_t* thr    = (uint32_t*)(ws + 524352);     // 64
    uint64_t* cand   = (uint64_t*)(ws + 524416);     // -> 1572992
    float4*   boxes  = (float4*)  (ws + 1572992);    // -> 3108992
    float*    scores = (float*)   (ws + 3108992);    // -> 3492992
    uint64_t* supp   = (uint64_t*)(ws + 3492992);    // 16*512*96*8 = 6291456 -> 9784448
    uint32_t* flags  = (uint32_t*)(ws + 9784448);    // 64
    uint32_t* tsave  = (uint32_t*)(ws + 9784512);    // 64
    uint64_t* aliveS = (uint64_t*)(ws + 9784576);    // -> 9796608
    uint32_t* idx    = (uint32_t*)(ws + 9796608);    // -> 9815808
    uint32_t* keys   = (uint32_t*)(ws + 9815808);    // -> 28690176
    uint64_t* cand2  = (uint64_t*)(ws + 28690176);   // 1048576 -> 29738752

    k_zero       <<<129, 256, 0, stream>>>((uint4*)ghist, cnt);
    k_hist       <<<1024, 256, 0, stream>>>(lab, reg, ghist, keys);
    k_thresh     <<<NBATCH, 256, 0, stream>>>(ghist, thr);
    k_compact    <<<2048, 256, 0, stream>>>(keys, thr, cnt, cand);
    k_sortA      <<<NBATCH * 8, 512, 0, stream>>>(cnt, cand);
    k_merge      <<<NBATCH * CAPN / 256, 256, 0, stream>>>(cand, cand2, 10);  // 1024 -> 2048
    k_merge      <<<NBATCH * CAPN / 256, 256, 0, stream>>>(cand2, cand, 11);  // 2048 -> 4096
    k_mergegather<<<(NBATCH * PRE + 255) / 256, 256, 0, stream>>>(cand, lab, reg, boxes, scores);
    k_iou        <<<NBATCH * 32, 512, 0, stream>>>(boxes, supp);
    k_walk       <<<NBATCH, 64, 0, stream>>>(supp, flags, tsave, aliveS, idx);
    k_resume     <<<NBATCH, 512, 0, stream>>>(boxes, flags, tsave, aliveS, idx);
    k_out        <<<(NBATCH * POST + 255) / 256, 256, 0, stream>>>(boxes, scores, idx, out);
}

// Round 18
// 194.017 us; speedup vs baseline: 1.0021x; 1.0021x over previous
//
#include <hip/hip_runtime.h>
#include <stdint.h>

#define NBATCH 16
#define NANCH  9
#define NHGT   128
#define NWID   256
#define NHW    (NHGT * NWID)       // 32768
#define NTOT   (NHW * NANCH)       // 294912
#define PRE    6000
#define POST   300
#define CAPN   8192
#define BINS   8192
#define BIN_SHIFT 19
#define NWORDS 94                  // ceil(6000/64)
#define NWSTRIDE 96                // padded row stride (words) -> 768 B, 16B-aligned
#define RROWS  512                 // suppression-matrix rows (exact fallback beyond)
#define NGROUPS (RROWS / 8)        // 64 groups of 8 rows
#define JHALF  3072                // j-split point for k_iou (words 0..47 | 48..93)
#define JREM   (PRE - JHALF)       // 2928

// exact replacement for (div_rn(inter,uni) > 0.7f):  (double)inter >= (double)uni * M
#define MIDP 0x1.6666668p-1

__device__ __constant__ float c_AW[NANCH] = {184.f,368.f,736.f,128.f,256.f,512.f,88.f,176.f,352.f};
__device__ __constant__ float c_AH[NANCH] = {96.f,192.f,384.f,128.f,256.f,512.f,176.f,352.f,704.f};

__device__ __forceinline__ uint32_t f2key(float f) {
    uint32_t u = __float_as_uint(f);
    return (u & 0x80000000u) ? ~u : (u | 0x80000000u);
}

__device__ __forceinline__ bool iou_sup(const float4 bi, float areaI, const float4 bj, float areaJ) {
    float xx1 = fmaxf(bi.x, bj.x);
    float yy1 = fmaxf(bi.y, bj.y);
    float xx2 = fminf(bi.z, bj.z);
    float yy2 = fminf(bi.w, bj.w);
    float iw = fmaxf(__fadd_rn(__fsub_rn(xx2, xx1), 1.f), 0.f);
    float ih = fmaxf(__fadd_rn(__fsub_rn(yy2, yy1), 1.f), 0.f);
    float inter = __fmul_rn(iw, ih);
    float uni = __fsub_rn(__fadd_rn(areaI, areaJ), inter);
    return ((double)inter >= (double)uni * MIDP);
}

__device__ __forceinline__ bool decode_clip(float dx, float dy, float dw, float dh,
                                            float aw, float ah, float acx, float acy,
                                            float& x1, float& y1, float& x2, float& y2) {
    float pcx = __fadd_rn(__fmul_rn(dx, aw), acx);
    float pcy = __fadd_rn(__fmul_rn(dy, ah), acy);
    float pw  = __fmul_rn(expf(dw), aw);
    float ph  = __fmul_rn(expf(dh), ah);
    float hx  = __fmul_rn(0.5f, pw);
    float hy  = __fmul_rn(0.5f, ph);
    x1 = __fsub_rn(pcx, hx);
    y1 = __fsub_rn(pcy, hy);
    x2 = __fadd_rn(pcx, hx);
    y2 = __fadd_rn(pcy, hy);
    x1 = fminf(fmaxf(x1, 0.f), 4095.f);
    x2 = fminf(fmaxf(x2, 0.f), 4095.f);
    y1 = fminf(fmaxf(y1, 0.f), 2047.f);
    y2 = fminf(fmaxf(y2, 0.f), 2047.f);
    float wpl = __fadd_rn(__fsub_rn(x2, x1), 1.f);
    float hpl = __fadd_rn(__fsub_rn(y2, y1), 1.f);
    return (wpl >= 16.f) && (hpl >= 16.f);
}

// ---------------- K0: zero ghist + cnt + thr (replaces slow runtime fill) ----------------
__global__ __launch_bounds__(256) void k_zero(uint4* __restrict__ ghist4,
                                              uint32_t* __restrict__ cntthr) {
    int g = blockIdx.x * 256 + threadIdx.x;
    if (blockIdx.x < 128) {
        ghist4[g] = make_uint4(0, 0, 0, 0);      // 128*256*16 = 524288 B
    } else {
        if (threadIdx.x < 32) cntthr[threadIdx.x] = 0;   // cnt(64B) + thr(64B)
    }
}

// ---------------- K1: LDS histogram (1024 blocks, float2 loads) + key array ----------------
__global__ __launch_bounds__(256) void k_hist(const float* __restrict__ lab,
                                              const float* __restrict__ reg,
                                              uint32_t* __restrict__ ghist,
                                              uint32_t* __restrict__ keys) {
    __shared__ uint32_t hist[BINS];
    for (int i = threadIdx.x; i < BINS; i += 256) hist[i] = 0;
    __syncthreads();
    int b = blockIdx.x >> 6, sub = blockIdx.x & 63;
    int hw = (sub << 9) | (threadIdx.x << 1);
    int h = hw >> 8, w = hw & 255;
    const float* lb = lab + (size_t)b * 18 * NHW + hw;
    const float* rb = reg + (size_t)b * 36 * NHW + hw;
    uint32_t* kb = keys + (size_t)b * NANCH * NHW + hw;
    float acx0 = (float)(w * 16) + 7.5f;
    float acx1 = acx0 + 16.0f;
    float acy  = (float)(h * 16) + 7.5f;
#pragma unroll
    for (int a = 0; a < NANCH; ++a) {
        float2 s  = *(const float2*)&lb[(2 * a + 1) * NHW];
        float2 dx = *(const float2*)&rb[(4 * a + 0) * NHW];
        float2 dy = *(const float2*)&rb[(4 * a + 1) * NHW];
        float2 dwv = *(const float2*)&rb[(4 * a + 2) * NHW];
        float2 dhv = *(const float2*)&rb[(4 * a + 3) * NHW];
        float x1, y1, x2, y2;
        bool k0 = decode_clip(dx.x, dy.x, dwv.x, dhv.x, c_AW[a], c_AH[a], acx0, acy, x1, y1, x2, y2);
        bool k1 = decode_clip(dx.y, dy.y, dwv.y, dhv.y, c_AW[a], c_AH[a], acx1, acy, x1, y1, x2, y2);
        uint32_t key0 = f2key(k0 ? s.x : -1e30f);
        uint32_t key1 = f2key(k1 ? s.y : -1e30f);
        *(uint2*)&kb[a * NHW] = make_uint2(key0, key1);
        atomicAdd(&hist[key0 >> BIN_SHIFT], 1u);
        atomicAdd(&hist[key1 >> BIN_SHIFT], 1u);
    }
    __syncthreads();
    uint32_t* gh = ghist + ((size_t)b << 13);
    for (int i = threadIdx.x; i < BINS; i += 256) {
        uint32_t c = hist[i];
        if (c) atomicAdd(&gh[i], c);
    }
}

// ---------------- K2: find threshold bin (cumulative from top >= PRE) ----------------
__global__ __launch_bounds__(256) void k_thresh(const uint32_t* __restrict__ ghist,
                                                uint32_t* __restrict__ thresh) {
    __shared__ uint32_t part[256];
    int b = blockIdx.x;
    const uint32_t* gh = ghist + ((size_t)b << 13);
    uint32_t p = 0;
    int base = threadIdx.x * 32;
    for (int k = 0; k < 32; ++k) p += gh[base + k];
    part[threadIdx.x] = p;
    __syncthreads();
    if (threadIdx.x == 0) {
        uint32_t cum = 0;
        int tb = 0;
        for (int c = 255; c >= 0; --c) {
            if (cum + part[c] >= (uint32_t)PRE) {
                for (int i = 31; i >= 0; --i) {
                    cum += gh[c * 32 + i];
                    if (cum >= (uint32_t)PRE) { tb = c * 32 + i; break; }
                }
                break;
            }
            cum += part[c];
        }
        thresh[b] = (uint32_t)tb << BIN_SHIFT;
    }
}

// ---------------- K3: compact from key array; LDS staging, 1 atomic/block ----------------
__global__ __launch_bounds__(256) void k_compact(const uint32_t* __restrict__ keys,
                                                 const uint32_t* __restrict__ thresh,
                                                 uint32_t* __restrict__ cnt,
                                                 uint64_t* __restrict__ cand) {
    __shared__ uint64_t stage[2304];
    __shared__ uint32_t sCount;
    __shared__ uint32_t sBase;
    if (threadIdx.x == 0) sCount = 0;
    __syncthreads();
    int bid = blockIdx.x;
    int b = bid >> 7;
    int hw = ((bid & 127) << 8) | threadIdx.x;
    int lane = threadIdx.x & 63;
    const uint32_t* kb = keys + (size_t)b * NANCH * NHW + hw;
    uint32_t th = thresh[b];
#pragma unroll
    for (int a = 0; a < NANCH; ++a) {
        uint32_t key = kb[a * NHW];
        bool valid = (key >= th);
        uint64_t mask = __ballot(valid);
        if (mask) {
            int leader = __ffsll((unsigned long long)mask) - 1;
            uint32_t wb = 0;
            if (lane == leader) wb = atomicAdd(&sCount, (uint32_t)__popcll(mask));
            wb = (uint32_t)__shfl((int)wb, leader);
            if (valid) {
                int rank = __popcll(mask & ((1ull << lane) - 1ull));
                uint32_t n = (uint32_t)(hw * NANCH + a);
                stage[wb + rank] = ((uint64_t)key << 32) | (uint32_t)(~n);
            }
        }
    }
    __syncthreads();
    if (threadIdx.x == 0) sBase = atomicAdd(&cnt[b], sCount);
    __syncthreads();
    uint32_t total = sCount, base = sBase;
    for (uint32_t i = threadIdx.x; i < total; i += 256) {
        uint32_t pos = base + i;
        if (pos < (uint32_t)CAPN) cand[(size_t)b * CAPN + pos] = stage[i];
    }
}

// ---------------- K4a: sort each 1024-chunk DESCENDING (local bitonic) ----------------
__global__ __launch_bounds__(512) void k_sortA(const uint32_t* __restrict__ cnt,
                                               uint64_t* __restrict__ cand) {
    __shared__ uint64_t sm[1024];            // 8 KiB
    int b = blockIdx.x >> 3, c = blockIdx.x & 7;
    uint32_t C = cnt[b];
    if (C > (uint32_t)CAPN) C = CAPN;
    uint64_t* cb = cand + (size_t)b * CAPN;
    int base = c << 10;
    for (int li = threadIdx.x; li < 1024; li += 512) {
        int gi = base + li;
        sm[li] = (gi < (int)C) ? cb[gi] : 0ull;
    }
    __syncthreads();
    for (int k = 2; k <= 1024; k <<= 1) {
        for (int j = k >> 1; j > 0; j >>= 1) {
            for (int li = threadIdx.x; li < 1024; li += 512) {
                int lxj = li ^ j;
                if (lxj > li) {
                    uint64_t va = sm[li], vb = sm[lxj];
                    bool up = ((li & k) == 0);
                    bool sw = up ? (va < vb) : (va > vb);
                    if (sw) { sm[li] = vb; sm[lxj] = va; }
                }
            }
            __syncthreads();
        }
    }
    for (int li = threadIdx.x; li < 1024; li += 512) cb[base + li] = sm[li];
}

// ---------------- K4b: pairwise merge-path (desc runs of length R=1<<Rlog) --------------
__global__ __launch_bounds__(256) void k_merge(const uint64_t* __restrict__ src,
                                               uint64_t* __restrict__ dst,
                                               int Rlog) {
    int g = blockIdx.x * 256 + threadIdx.x;
    if (g >= NBATCH * CAPN) return;
    int b = g >> 13;
    int p = g & (CAPN - 1);
    int R = 1 << Rlog;
    int pair = p >> (Rlog + 1);
    int q = p & ((R << 1) - 1);
    const uint64_t* A = src + (size_t)b * CAPN + ((size_t)(pair << 1) << Rlog);
    const uint64_t* B = A + R;
    int lo = (q > R) ? (q - R) : 0;
    int hi = (q < R) ? q : R;
    while (lo < hi) {
        int mid = (lo + hi) >> 1;
        if (A[mid] > B[q - mid - 1]) lo = mid + 1; else hi = mid;
    }
    int i = lo, j = q - lo;
    uint64_t aV = (i < R) ? A[i] : 0ull;
    uint64_t bV = (j < R) ? B[j] : 0ull;
    dst[(size_t)b * CAPN + p] = (aV > bV) ? aV : bV;
}

// ---------------- K4c: merge-path top-PRE over two DESC 4096-runs + gather/decode -------
__global__ __launch_bounds__(256) void k_mergegather(const uint64_t* __restrict__ cand,
                                                     const float* __restrict__ lab,
                                                     const float* __restrict__ reg,
                                                     float4* __restrict__ boxes,
                                                     float* __restrict__ scores) {
    int g = blockIdx.x * 256 + threadIdx.x;
    if (g >= NBATCH * PRE) return;
    int b = g / PRE, p = g - b * PRE;
    const uint64_t* A = cand + (size_t)b * CAPN;
    const uint64_t* B = A + 4096;
    int lo = (p > 4096) ? (p - 4096) : 0;
    int hi = (p < 4096) ? p : 4096;
    while (lo < hi) {
        int mid = (lo + hi) >> 1;
        if (A[mid] > B[p - mid - 1]) lo = mid + 1; else hi = mid;
    }
    int i = lo, j = p - lo;
    uint64_t aV = (i < 4096) ? A[i] : 0ull;
    uint64_t bV = (j < 4096) ? B[j] : 0ull;
    uint64_t v = (aV > bV) ? aV : bV;
    uint32_t n = ~(uint32_t)(v & 0xFFFFFFFFull);
    if (n >= (uint32_t)NTOT) n = 0;
    int a = (int)(n % NANCH);
    int hw = (int)(n / NANCH);
    int w = hw & 255, h = hw >> 8;
    const float* lb0 = lab + (size_t)b * 18 * NHW;
    const float* rb0 = reg + (size_t)b * 36 * NHW;
    float s  = lb0[(2 * a + 1) * NHW + hw];
    float dx = rb0[(4 * a + 0) * NHW + hw];
    float dy = rb0[(4 * a + 1) * NHW + hw];
    float dwv = rb0[(4 * a + 2) * NHW + hw];
    float dhv = rb0[(4 * a + 3) * NHW + hw];
    float acx = (float)(w * 16) + 7.5f;
    float acy = (float)(h * 16) + 7.5f;
    float x1, y1, x2, y2;
    decode_clip(dx, dy, dwv, dhv, c_AW[a], c_AH[a], acx, acy, x1, y1, x2, y2);
    boxes[b * PRE + p] = make_float4(x1, y1, x2, y2);
    scores[b * PRE + p] = s;
}

// ---------------- K6a: suppression bit-matrix, j-split halves, 2 rows per pass ----------
__global__ __launch_bounds__(512) void k_iou(const float4* __restrict__ boxes,
                                             uint64_t* __restrict__ supp) {
    __shared__ float4 lb[JHALF];
    __shared__ float  la[JHALF];
    int half = blockIdx.x & 1;
    int rblk = (blockIdx.x >> 1) & 15;
    int b    = blockIdx.x >> 5;
    const float4* bb = boxes + b * PRE;
    int jbase  = half ? JHALF : 0;
    int jcount = half ? JREM : JHALF;
    for (int i = threadIdx.x; i < jcount; i += 512) {
        float4 v = bb[jbase + i];
        lb[i] = v;
        la[i] = __fmul_rn(__fadd_rn(__fsub_rn(v.z, v.x), 1.f),
                          __fadd_rn(__fsub_rn(v.w, v.y), 1.f));
    }
    __syncthreads();
    int wave = threadIdx.x >> 6, lane = threadIdx.x & 63;
    int wlo = half ? 48 : 0;
    int whi = half ? NWORDS : 48;
#pragma unroll 1
    for (int m = 0; m < 2; ++m) {
        int r0 = rblk + 16 * wave + 128 * m;     // < 256
        int r1 = r0 + 256;                       // < 512
        float4 bi0 = bb[r0];
        float4 bi1 = bb[r1];
        float a0 = __fmul_rn(__fadd_rn(__fsub_rn(bi0.z, bi0.x), 1.f),
                             __fadd_rn(__fsub_rn(bi0.w, bi0.y), 1.f));
        float a1 = __fmul_rn(__fadd_rn(__fsub_rn(bi1.z, bi1.x), 1.f),
                             __fadd_rn(__fsub_rn(bi1.w, bi1.y), 1.f));
        uint64_t keep0 = 0ull, keep1 = 0ull;
        int w0 = r0 >> 6;                        // <= 3
        int wstart = (wlo > w0) ? wlo : w0;
        for (int w = wstart; w < whi; ++w) {
            int j = (w << 6) | lane;
            bool s0 = false, s1 = false;
            if (j < PRE) {
                int idx = j - jbase;
                float4 bj = lb[idx];
                float aj = la[idx];
                s0 = iou_sup(bi0, a0, bj, aj);
                s1 = iou_sup(bi1, a1, bj, aj);
            }
            uint64_t m0 = __ballot(s0);
            uint64_t m1 = __ballot(s1);
            if (lane == w - wlo) { keep0 = m0; keep1 = m1; }
        }
        uint64_t* sr0 = supp + ((size_t)b * RROWS + r0) * NWSTRIDE;
        uint64_t* sr1 = supp + ((size_t)b * RROWS + r1) * NWSTRIDE;
        if (half == 0) {
            if (lane < 48) { sr0[lane] = keep0; sr1[lane] = keep1; }
        } else {
            if (lane < 48) {
                sr0[48 + lane] = (lane < 46) ? keep0 : 0ull;
                sr1[48 + lane] = (lane < 46) ? keep1 : 0ull;
            }
        }
    }
}

// ---------------- K6b: sequential walk; 6-buffer pinned prefetch; UNIFORM loads ----------
#define ISSUE(BUF, GRP) do {                                                               \
    int _g = (GRP); if (_g > NGROUPS - 1) _g = NGROUPS - 1;                                \
    int _jb = _g << 3;                                                                     \
    const ulonglong2* _p = (const ulonglong2*)(sbase + (size_t)_jb * NWSTRIDE) + lclamp;   \
    BUF##0 = _p[0];   BUF##1 = _p[48];  BUF##2 = _p[96];  BUF##3 = _p[144];                \
    BUF##4 = _p[192]; BUF##5 = _p[240]; BUF##6 = _p[288]; BUF##7 = _p[336];                \
    __builtin_amdgcn_sched_barrier(0);  /* pin: loads stay issued HERE, not sunk */        \
} while (0)

#define ROWP(RD, JB, R) {                                                                  \
    if (((curw >> (((JB) & 63) + (R))) & 1ull) != 0ull) {                                  \
        if (lane == 0) idxb[t] = (uint32_t)((JB) + (R));                                   \
        v0 &= ~RD.x; v1 &= ~RD.y;                                                          \
        int _w = ((JB) + (R)) >> 6;                                                        \
        uint64_t _sw = (uint64_t)__shfl((long long)((_w & 1) ? RD.y : RD.x), _w >> 1);     \
        curw &= ~_sw;                                                                      \
        ++t;                                                                               \
        if (t >= POST) goto walk_done;                                                     \
    }                                                                                      \
}

#define PROC(BUF, GRP) do {                                                                \
    int _jb2 = (GRP) << 3;                                                                 \
    if ((_jb2 & 63) == 0) {                                                                \
        int _wi = _jb2 >> 6;                                                               \
        uint64_t _c0 = (uint64_t)__shfl((long long)v0, _wi >> 1);                          \
        uint64_t _c1 = (uint64_t)__shfl((long long)v1, _wi >> 1);                          \
        curw = (_wi & 1) ? _c1 : _c0;                                                      \
    }                                                                                      \
    ROWP(BUF##0, _jb2, 0); ROWP(BUF##1, _jb2, 1); ROWP(BUF##2, _jb2, 2); ROWP(BUF##3, _jb2, 3); \
    ROWP(BUF##4, _jb2, 4); ROWP(BUF##5, _jb2, 5); ROWP(BUF##6, _jb2, 6); ROWP(BUF##7, _jb2, 7); \
} while (0)

__global__ __launch_bounds__(64, 1) void k_walk(const uint64_t* __restrict__ supp,
                                                uint32_t* __restrict__ flags,
                                                uint32_t* __restrict__ tsave,
                                                uint64_t* __restrict__ aliveSv,
                                                uint32_t* __restrict__ idxAll) {
    int b = blockIdx.x;
    int lane = threadIdx.x;
    int lclamp = (lane < 48) ? lane : 47;
    uint32_t* idxb = idxAll + b * POST;
    const uint64_t* sbase = supp + (size_t)b * RROWS * NWSTRIDE;
    uint64_t v0, v1;
    if (lane < 46)       { v0 = ~0ull; v1 = ~0ull; }
    else if (lane == 46) { v0 = ~0ull; v1 = (1ull << 48) - 1ull; }
    else                 { v0 = 0ull;  v1 = 0ull; }
    uint64_t curw = 0;
    int t = 0;
    int flag = 0;
    ulonglong2 A0,A1,A2,A3,A4,A5,A6,A7;
    ulonglong2 B0,B1,B2,B3,B4,B5,B6,B7;
    ulonglong2 C0,C1,C2,C3,C4,C5,C6,C7;
    ulonglong2 D0,D1,D2,D3,D4,D5,D6,D7;
    ulonglong2 E0,E1,E2,E3,E4,E5,E6,E7;
    ulonglong2 F0,F1,F2,F3,F4,F5,F6,F7;
    ISSUE(A, 0); ISSUE(B, 1); ISSUE(C, 2); ISSUE(D, 3); ISSUE(E, 4); ISSUE(F, 5);
    // NGROUPS = 64 = 10*6 + 4: main loop covers groups 0..59, tail covers 60..63.
    for (int g = 0; g < NGROUPS - 4; g += 6) {
        PROC(A, g);     ISSUE(A, g + 6);
        PROC(B, g + 1); ISSUE(B, g + 7);
        PROC(C, g + 2); ISSUE(C, g + 8);
        PROC(D, g + 3); ISSUE(D, g + 9);
        PROC(E, g + 4); ISSUE(E, g + 10);
        PROC(F, g + 5); ISSUE(F, g + 11);
    }
    PROC(A, NGROUPS - 4); PROC(B, NGROUPS - 3); PROC(C, NGROUPS - 2); PROC(D, NGROUPS - 1);
    {
        unsigned long long anyAlive = __ballot((v0 | v1) != 0ull);
        if (anyAlive == 0ull) {
            if (lane == 0) for (int tt = t; tt < POST; ++tt) idxb[tt] = 0u;
        } else {
            if (2 * lane < NWORDS)     aliveSv[b * NWORDS + 2 * lane] = v0;
            if (2 * lane + 1 < NWORDS) aliveSv[b * NWORDS + 2 * lane + 1] = v1;
            if (lane == 0) tsave[b] = (uint32_t)t;
            flag = 1;
        }
    }
walk_done:
    if (lane == 0) flags[b] = (uint32_t)flag;
}

// ---------------- K6c: rare exact fallback; records indices; early-exit flag==0 ----------
__global__ __launch_bounds__(512) void k_resume(const float4* __restrict__ boxes,
                                                const uint32_t* __restrict__ flags,
                                                const uint32_t* __restrict__ tsave,
                                                const uint64_t* __restrict__ aliveSv,
                                                uint32_t* __restrict__ idxAll) {
    int b = blockIdx.x;
    if (flags[b] == 0) return;
    __shared__ uint64_t alive[NWORDS];
    __shared__ uint32_t sCur;
    int tid = threadIdx.x;
    const float4* bb = boxes + b * PRE;
    uint32_t* idxb = idxAll + b * POST;
    if (tid < NWORDS) alive[tid] = aliveSv[b * NWORDS + tid];
    __syncthreads();
    int t0 = (int)tsave[b];
    for (int t = t0; t < POST; ++t) {
        if (tid == 0) sCur = 0xFFFFFFFFu;
        __syncthreads();
        if (tid < NWORDS) {
            uint64_t wd = alive[tid];
            if (wd) atomicMin(&sCur, (uint32_t)(tid * 64 + (__ffsll((unsigned long long)wd) - 1)));
        }
        __syncthreads();
        uint32_t cur = sCur;
        uint32_t e = (cur < (uint32_t)PRE) ? cur : 0u;
        if (tid == 0) {
            idxb[t] = e;
            if (cur < (uint32_t)PRE)
                atomicAnd(&alive[cur >> 6], ~(1ull << (cur & 63)));
        }
        if (cur < (uint32_t)PRE) {
            float4 bc = bb[e];
            float areaC = __fmul_rn(__fadd_rn(__fsub_rn(bc.z, bc.x), 1.f),
                                    __fadd_rn(__fsub_rn(bc.w, bc.y), 1.f));
            for (uint32_t j = cur + 1 + tid; j < (uint32_t)PRE; j += 512) {
                uint64_t wd = alive[j >> 6];
                if ((wd >> (j & 63)) & 1ull) {
                    float4 bj = bb[j];
                    float areaJ = __fmul_rn(__fadd_rn(__fsub_rn(bj.z, bj.x), 1.f),
                                            __fadd_rn(__fsub_rn(bj.w, bj.y), 1.f));
                    if (iou_sup(bc, areaC, bj, areaJ))
                        atomicAnd(&alive[j >> 6], ~(1ull << (j & 63)));
                }
            }
        }
        __syncthreads();
    }
}

// ---------------- K7: gather emitted indices -> output boxes + scores ----------------
__global__ __launch_bounds__(256) void k_out(const float4* __restrict__ boxes,
                                             const float* __restrict__ scores,
                                             const uint32_t* __restrict__ idxAll,
                                             float* __restrict__ out) {
    int g = blockIdx.x * 256 + threadIdx.x;
    if (g >= NBATCH * POST) return;
    int b = g / POST;
    uint32_t i = idxAll[g];
    if (i >= (uint32_t)PRE) i = 0;
    float4 bc = boxes[b * PRE + i];
    size_t ob = (size_t)g * 4;
    out[ob + 0] = bc.x; out[ob + 1] = bc.y;
    out[ob + 2] = bc.z; out[ob + 3] = bc.w;
    out[(size_t)NBATCH * POST * 4 + g] = scores[b * PRE + i];
}

extern "C" void kernel_launch(void* const* d_in, const int* in_sizes, int n_in,
                              void* d_out, int out_size, void* d_ws, size_t ws_size,
                              hipStream_t stream) {
    (void)in_sizes; (void)n_in; (void)out_size; (void)ws_size;
    const float* lab = (const float*)d_in[0];
    const float* reg = (const float*)d_in[1];
    float* out = (float*)d_out;
    char* ws = (char*)d_ws;

    // workspace layout (bytes)
    uint32_t* ghist  = (uint32_t*)(ws + 0);          // 16*8192*4 = 524288
    uint32_t* cnt    = (uint32_t*)(ws + 524288);     // 64
    uint32_t* thr    = (uint32_t*)(ws + 524352);     // 64
    uint64_t* cand   = (uint64_t*)(ws + 524416);     // -> 1572992
    float4*   boxes  = (float4*)  (ws + 1572992);    // -> 3108992
    float*    scores = (float*)   (ws + 3108992);    // -> 3492992
    uint64_t* supp   = (uint64_t*)(ws + 3492992);    // 16*512*96*8 = 6291456 -> 9784448
    uint32_t* flags  = (uint32_t*)(ws + 9784448);    // 64
    uint32_t* tsave  = (uint32_t*)(ws + 9784512);    // 64
    uint64_t* aliveS = (uint64_t*)(ws + 9784576);    // -> 9796608
    uint32_t* idx    = (uint32_t*)(ws + 9796608);    // -> 9815808
    uint32_t* keys   = (uint32_t*)(ws + 9815808);    // -> 28690176
    uint64_t* cand2  = (uint64_t*)(ws + 28690176);   // 1048576 -> 29738752

    k_zero       <<<129, 256, 0, stream>>>((uint4*)ghist, cnt);
    k_hist       <<<1024, 256, 0, stream>>>(lab, reg, ghist, keys);
    k_thresh     <<<NBATCH, 256, 0, stream>>>(ghist, thr);
    k_compact    <<<2048, 256, 0, stream>>>(keys, thr, cnt, cand);
    k_sortA      <<<NBATCH * 8, 512, 0, stream>>>(cnt, cand);
    k_merge      <<<NBATCH * CAPN / 256, 256, 0, stream>>>(cand, cand2, 10);  // 1024 -> 2048
    k_merge      <<<NBATCH * CAPN / 256, 256, 0, stream>>>(cand2, cand, 11);  // 2048 -> 4096
    k_mergegather<<<(NBATCH * PRE + 255) / 256, 256, 0, stream>>>(cand, lab, reg, boxes, scores);
    k_iou        <<<NBATCH * 32, 512, 0, stream>>>(boxes, supp);
    k_walk       <<<NBATCH, 64, 0, stream>>>(supp, flags, tsave, aliveS, idx);
    k_resume     <<<NBATCH, 512, 0, stream>>>(boxes, flags, tsave, aliveS, idx);
    k_out        <<<(NBATCH * POST + 255) / 256, 256, 0, stream>>>(boxes, scores, idx, out);
}

// Round 19
// 182.820 us; speedup vs baseline: 1.0634x; 1.0612x over previous
//
#include <hip/hip_runtime.h>
#include <stdint.h>

#define NBATCH 16
#define NANCH  9
#define NHGT   128
#define NWID   256
#define NHW    (NHGT * NWID)       // 32768
#define NTOT   (NHW * NANCH)       // 294912
#define PRE    6000
#define POST   300
#define CAPN   8192
#define BINS   8192
#define BIN_SHIFT 19
#define NWORDS 94                  // ceil(6000/64)
#define NWSTRIDE 96                // padded row stride (words) -> 768 B, 16B-aligned
#define RROWS  384                 // suppression-matrix rows (exact fallback beyond)
#define NGROUPS (RROWS / 8)        // 48 groups of 8 rows (= 8 x 6-buffer rounds)
#define JQ     1536                // j-quarter size for k_iou (24 words each)

// exact replacement for (div_rn(inter,uni) > 0.7f):  (double)inter >= (double)uni * M
#define MIDP 0x1.6666668p-1

__device__ __constant__ float c_AW[NANCH] = {184.f,368.f,736.f,128.f,256.f,512.f,88.f,176.f,352.f};
__device__ __constant__ float c_AH[NANCH] = {96.f,192.f,384.f,128.f,256.f,512.f,176.f,352.f,704.f};

__device__ __forceinline__ uint32_t f2key(float f) {
    uint32_t u = __float_as_uint(f);
    return (u & 0x80000000u) ? ~u : (u | 0x80000000u);
}

__device__ __forceinline__ bool iou_sup(const float4 bi, float areaI, const float4 bj, float areaJ) {
    float xx1 = fmaxf(bi.x, bj.x);
    float yy1 = fmaxf(bi.y, bj.y);
    float xx2 = fminf(bi.z, bj.z);
    float yy2 = fminf(bi.w, bj.w);
    float iw = fmaxf(__fadd_rn(__fsub_rn(xx2, xx1), 1.f), 0.f);
    float ih = fmaxf(__fadd_rn(__fsub_rn(yy2, yy1), 1.f), 0.f);
    float inter = __fmul_rn(iw, ih);
    float uni = __fsub_rn(__fadd_rn(areaI, areaJ), inter);
    return ((double)inter >= (double)uni * MIDP);
}

__device__ __forceinline__ bool decode_clip(float dx, float dy, float dw, float dh,
                                            float aw, float ah, float acx, float acy,
                                            float& x1, float& y1, float& x2, float& y2) {
    float pcx = __fadd_rn(__fmul_rn(dx, aw), acx);
    float pcy = __fadd_rn(__fmul_rn(dy, ah), acy);
    float pw  = __fmul_rn(expf(dw), aw);
    float ph  = __fmul_rn(expf(dh), ah);
    float hx  = __fmul_rn(0.5f, pw);
    float hy  = __fmul_rn(0.5f, ph);
    x1 = __fsub_rn(pcx, hx);
    y1 = __fsub_rn(pcy, hy);
    x2 = __fadd_rn(pcx, hx);
    y2 = __fadd_rn(pcy, hy);
    x1 = fminf(fmaxf(x1, 0.f), 4095.f);
    x2 = fminf(fmaxf(x2, 0.f), 4095.f);
    y1 = fminf(fmaxf(y1, 0.f), 2047.f);
    y2 = fminf(fmaxf(y2, 0.f), 2047.f);
    float wpl = __fadd_rn(__fsub_rn(x2, x1), 1.f);
    float hpl = __fadd_rn(__fsub_rn(y2, y1), 1.f);
    return (wpl >= 16.f) && (hpl >= 16.f);
}

// ---------------- K0: zero ghist + cnt + thr ----------------
__global__ __launch_bounds__(256) void k_zero(uint4* __restrict__ ghist4,
                                              uint32_t* __restrict__ cntthr) {
    int g = blockIdx.x * 256 + threadIdx.x;
    if (blockIdx.x < 128) {
        ghist4[g] = make_uint4(0, 0, 0, 0);
    } else {
        if (threadIdx.x < 32) cntthr[threadIdx.x] = 0;
    }
}

// ---------------- K1: LDS histogram (512 blocks, float4 loads) + key array ----------------
__global__ __launch_bounds__(256) void k_hist(const float* __restrict__ lab,
                                              const float* __restrict__ reg,
                                              uint32_t* __restrict__ ghist,
                                              uint32_t* __restrict__ keys) {
    __shared__ uint32_t hist[BINS];
    for (int i = threadIdx.x; i < BINS; i += 256) hist[i] = 0;
    __syncthreads();
    int b = blockIdx.x >> 5, sub = blockIdx.x & 31;
    int hw = (sub << 10) | (threadIdx.x << 2);
    int h = hw >> 8, w = hw & 255;
    const float* lb = lab + (size_t)b * 18 * NHW + hw;
    const float* rb = reg + (size_t)b * 36 * NHW + hw;
    uint32_t* kb = keys + (size_t)b * NANCH * NHW + hw;
    float acy  = (float)(h * 16) + 7.5f;
    float acx0 = (float)(w * 16) + 7.5f;
    float acx1 = acx0 + 16.0f;
    float acx2 = acx0 + 32.0f;
    float acx3 = acx0 + 48.0f;
#pragma unroll
    for (int a = 0; a < NANCH; ++a) {
        float4 s  = *(const float4*)&lb[(2 * a + 1) * NHW];
        float4 dx = *(const float4*)&rb[(4 * a + 0) * NHW];
        float4 dy = *(const float4*)&rb[(4 * a + 1) * NHW];
        float4 dwv = *(const float4*)&rb[(4 * a + 2) * NHW];
        float4 dhv = *(const float4*)&rb[(4 * a + 3) * NHW];
        float x1, y1, x2, y2;
        bool k0 = decode_clip(dx.x, dy.x, dwv.x, dhv.x, c_AW[a], c_AH[a], acx0, acy, x1, y1, x2, y2);
        bool k1 = decode_clip(dx.y, dy.y, dwv.y, dhv.y, c_AW[a], c_AH[a], acx1, acy, x1, y1, x2, y2);
        bool k2 = decode_clip(dx.z, dy.z, dwv.z, dhv.z, c_AW[a], c_AH[a], acx2, acy, x1, y1, x2, y2);
        bool k3 = decode_clip(dx.w, dy.w, dwv.w, dhv.w, c_AW[a], c_AH[a], acx3, acy, x1, y1, x2, y2);
        uint32_t key0 = f2key(k0 ? s.x : -1e30f);
        uint32_t key1 = f2key(k1 ? s.y : -1e30f);
        uint32_t key2 = f2key(k2 ? s.z : -1e30f);
        uint32_t key3 = f2key(k3 ? s.w : -1e30f);
        *(uint4*)&kb[a * NHW] = make_uint4(key0, key1, key2, key3);
        atomicAdd(&hist[key0 >> BIN_SHIFT], 1u);
        atomicAdd(&hist[key1 >> BIN_SHIFT], 1u);
        atomicAdd(&hist[key2 >> BIN_SHIFT], 1u);
        atomicAdd(&hist[key3 >> BIN_SHIFT], 1u);
    }
    __syncthreads();
    uint32_t* gh = ghist + ((size_t)b << 13);
    for (int i = threadIdx.x; i < BINS; i += 256) {
        uint32_t c = hist[i];
        if (c) atomicAdd(&gh[i], c);
    }
}

// ---------------- K2: find threshold bin (cumulative from top >= PRE) ----------------
__global__ __launch_bounds__(256) void k_thresh(const uint32_t* __restrict__ ghist,
                                                uint32_t* __restrict__ thresh) {
    __shared__ uint32_t part[256];
    int b = blockIdx.x;
    const uint32_t* gh = ghist + ((size_t)b << 13);
    uint32_t p = 0;
    int base = threadIdx.x * 32;
    for (int k = 0; k < 32; ++k) p += gh[base + k];
    part[threadIdx.x] = p;
    __syncthreads();
    if (threadIdx.x == 0) {
        uint32_t cum = 0;
        int tb = 0;
        for (int c = 255; c >= 0; --c) {
            if (cum + part[c] >= (uint32_t)PRE) {
                for (int i = 31; i >= 0; --i) {
                    cum += gh[c * 32 + i];
                    if (cum >= (uint32_t)PRE) { tb = c * 32 + i; break; }
                }
                break;
            }
            cum += part[c];
        }
        thresh[b] = (uint32_t)tb << BIN_SHIFT;
    }
}

// ---------------- K3: compact from key array; LDS staging, 1 atomic/block ----------------
__global__ __launch_bounds__(256) void k_compact(const uint32_t* __restrict__ keys,
                                                 const uint32_t* __restrict__ thresh,
                                                 uint32_t* __restrict__ cnt,
                                                 uint64_t* __restrict__ cand) {
    __shared__ uint64_t stage[2304];
    __shared__ uint32_t sCount;
    __shared__ uint32_t sBase;
    if (threadIdx.x == 0) sCount = 0;
    __syncthreads();
    int bid = blockIdx.x;
    int b = bid >> 7;
    int hw = ((bid & 127) << 8) | threadIdx.x;
    int lane = threadIdx.x & 63;
    const uint32_t* kb = keys + (size_t)b * NANCH * NHW + hw;
    uint32_t th = thresh[b];
#pragma unroll
    for (int a = 0; a < NANCH; ++a) {
        uint32_t key = kb[a * NHW];
        bool valid = (key >= th);
        uint64_t mask = __ballot(valid);
        if (mask) {
            int leader = __ffsll((unsigned long long)mask) - 1;
            uint32_t wb = 0;
            if (lane == leader) wb = atomicAdd(&sCount, (uint32_t)__popcll(mask));
            wb = (uint32_t)__shfl((int)wb, leader);
            if (valid) {
                int rank = __popcll(mask & ((1ull << lane) - 1ull));
                uint32_t n = (uint32_t)(hw * NANCH + a);
                stage[wb + rank] = ((uint64_t)key << 32) | (uint32_t)(~n);
            }
        }
    }
    __syncthreads();
    if (threadIdx.x == 0) sBase = atomicAdd(&cnt[b], sCount);
    __syncthreads();
    uint32_t total = sCount, base = sBase;
    for (uint32_t i = threadIdx.x; i < total; i += 256) {
        uint32_t pos = base + i;
        if (pos < (uint32_t)CAPN) cand[(size_t)b * CAPN + pos] = stage[i];
    }
}

// ---------------- K4a: sort each 1024-chunk DESCENDING (local bitonic) ----------------
__global__ __launch_bounds__(512) void k_sortA(const uint32_t* __restrict__ cnt,
                                               uint64_t* __restrict__ cand) {
    __shared__ uint64_t sm[1024];
    int b = blockIdx.x >> 3, c = blockIdx.x & 7;
    uint32_t C = cnt[b];
    if (C > (uint32_t)CAPN) C = CAPN;
    uint64_t* cb = cand + (size_t)b * CAPN;
    int base = c << 10;
    for (int li = threadIdx.x; li < 1024; li += 512) {
        int gi = base + li;
        sm[li] = (gi < (int)C) ? cb[gi] : 0ull;
    }
    __syncthreads();
    for (int k = 2; k <= 1024; k <<= 1) {
        for (int j = k >> 1; j > 0; j >>= 1) {
            for (int li = threadIdx.x; li < 1024; li += 512) {
                int lxj = li ^ j;
                if (lxj > li) {
                    uint64_t va = sm[li], vb = sm[lxj];
                    bool up = ((li & k) == 0);
                    bool sw = up ? (va < vb) : (va > vb);
                    if (sw) { sm[li] = vb; sm[lxj] = va; }
                }
            }
            __syncthreads();
        }
    }
    for (int li = threadIdx.x; li < 1024; li += 512) cb[base + li] = sm[li];
}

// ---------------- K4b: pairwise merge-path (desc runs of length R=1<<Rlog) --------------
__global__ __launch_bounds__(256) void k_merge(const uint64_t* __restrict__ src,
                                               uint64_t* __restrict__ dst,
                                               int Rlog) {
    int g = blockIdx.x * 256 + threadIdx.x;
    if (g >= NBATCH * CAPN) return;
    int b = g >> 13;
    int p = g & (CAPN - 1);
    int R = 1 << Rlog;
    int pair = p >> (Rlog + 1);
    int q = p & ((R << 1) - 1);
    const uint64_t* A = src + (size_t)b * CAPN + ((size_t)(pair << 1) << Rlog);
    const uint64_t* B = A + R;
    int lo = (q > R) ? (q - R) : 0;
    int hi = (q < R) ? q : R;
    while (lo < hi) {
        int mid = (lo + hi) >> 1;
        if (A[mid] > B[q - mid - 1]) lo = mid + 1; else hi = mid;
    }
    int i = lo, j = q - lo;
    uint64_t aV = (i < R) ? A[i] : 0ull;
    uint64_t bV = (j < R) ? B[j] : 0ull;
    dst[(size_t)b * CAPN + p] = (aV > bV) ? aV : bV;
}

// ---------------- K4c: merge-path top-PRE over two DESC 4096-runs + gather/decode -------
__global__ __launch_bounds__(256) void k_mergegather(const uint64_t* __restrict__ cand,
                                                     const float* __restrict__ lab,
                                                     const float* __restrict__ reg,
                                                     float4* __restrict__ boxes,
                                                     float* __restrict__ scores) {
    int g = blockIdx.x * 256 + threadIdx.x;
    if (g >= NBATCH * PRE) return;
    int b = g / PRE, p = g - b * PRE;
    const uint64_t* A = cand + (size_t)b * CAPN;
    const uint64_t* B = A + 4096;
    int lo = (p > 4096) ? (p - 4096) : 0;
    int hi = (p < 4096) ? p : 4096;
    while (lo < hi) {
        int mid = (lo + hi) >> 1;
        if (A[mid] > B[p - mid - 1]) lo = mid + 1; else hi = mid;
    }
    int i = lo, j = p - lo;
    uint64_t aV = (i < 4096) ? A[i] : 0ull;
    uint64_t bV = (j < 4096) ? B[j] : 0ull;
    uint64_t v = (aV > bV) ? aV : bV;
    uint32_t n = ~(uint32_t)(v & 0xFFFFFFFFull);
    if (n >= (uint32_t)NTOT) n = 0;
    int a = (int)(n % NANCH);
    int hw = (int)(n / NANCH);
    int w = hw & 255, h = hw >> 8;
    const float* lb0 = lab + (size_t)b * 18 * NHW;
    const float* rb0 = reg + (size_t)b * 36 * NHW;
    float s  = lb0[(2 * a + 1) * NHW + hw];
    float dx = rb0[(4 * a + 0) * NHW + hw];
    float dy = rb0[(4 * a + 1) * NHW + hw];
    float dwv = rb0[(4 * a + 2) * NHW + hw];
    float dhv = rb0[(4 * a + 3) * NHW + hw];
    float acx = (float)(w * 16) + 7.5f;
    float acy = (float)(h * 16) + 7.5f;
    float x1, y1, x2, y2;
    decode_clip(dx, dy, dwv, dhv, c_AW[a], c_AH[a], acx, acy, x1, y1, x2, y2);
    boxes[b * PRE + p] = make_float4(x1, y1, x2, y2);
    scores[b * PRE + p] = s;
}

// ---------------- K6a: suppression bit-matrix; j-quarters; 3 rows per j-pass ----------
// grid = b(16) x rblk(16) x quad(4) = 1024 blocks, 512 thr, ~30KB LDS.
// quad q covers words [24q, 24q+24) (quad3: 72..93 + pad). Wave handles rows
// (r, r+128, r+256), r = rblk + 16*wave in [0,128). Below-diagonal extra bits for
// r+128/r+256 are real IoU bits at dead positions (walk visits rows in increasing
// order) -> harmless.
__global__ __launch_bounds__(512) void k_iou(const float4* __restrict__ boxes,
                                             uint64_t* __restrict__ supp) {
    __shared__ float4 lb[JQ];                // 24576 B
    __shared__ float  la[JQ];                // 6144 B
    int quad = blockIdx.x & 3;
    int rblk = (blockIdx.x >> 2) & 15;
    int b    = blockIdx.x >> 6;
    const float4* bb = boxes + b * PRE;
    int jbase  = quad * JQ;
    int jcount = (quad == 3) ? (PRE - 3 * JQ) : JQ;   // 1392 or 1536
    for (int i = threadIdx.x; i < jcount; i += 512) {
        float4 v = bb[jbase + i];
        lb[i] = v;
        la[i] = __fmul_rn(__fadd_rn(__fsub_rn(v.z, v.x), 1.f),
                          __fadd_rn(__fsub_rn(v.w, v.y), 1.f));
    }
    __syncthreads();
    int wave = threadIdx.x >> 6, lane = threadIdx.x & 63;
    int wlo = quad * 24;
    int whi = (quad == 3) ? NWORDS : (wlo + 24);
    int r0 = rblk + 16 * wave;               // [0,128)
    int r1 = r0 + 128;
    int r2 = r0 + 256;
    float4 bi0 = bb[r0];
    float4 bi1 = bb[r1];
    float4 bi2 = bb[r2];
    float a0 = __fmul_rn(__fadd_rn(__fsub_rn(bi0.z, bi0.x), 1.f),
                         __fadd_rn(__fsub_rn(bi0.w, bi0.y), 1.f));
    float a1 = __fmul_rn(__fadd_rn(__fsub_rn(bi1.z, bi1.x), 1.f),
                         __fadd_rn(__fsub_rn(bi1.w, bi1.y), 1.f));
    float a2 = __fmul_rn(__fadd_rn(__fsub_rn(bi2.z, bi2.x), 1.f),
                         __fadd_rn(__fsub_rn(bi2.w, bi2.y), 1.f));
    uint64_t keep0 = 0ull, keep1 = 0ull, keep2 = 0ull;
    int w0 = r0 >> 6;                        // 0 or 1
    int wstart = (wlo > w0) ? wlo : w0;
    for (int w = wstart; w < whi; ++w) {
        int j = (w << 6) | lane;
        bool s0 = false, s1 = false, s2 = false;
        if (j < PRE) {
            int idx = j - jbase;
            float4 bj = lb[idx];
            float aj = la[idx];
            s0 = iou_sup(bi0, a0, bj, aj);
            s1 = iou_sup(bi1, a1, bj, aj);
            s2 = iou_sup(bi2, a2, bj, aj);
        }
        uint64_t m0 = __ballot(s0);
        uint64_t m1 = __ballot(s1);
        uint64_t m2 = __ballot(s2);
        if (lane == w - wlo) { keep0 = m0; keep1 = m1; keep2 = m2; }
    }
    uint64_t* sr0 = supp + ((size_t)b * RROWS + r0) * NWSTRIDE;
    uint64_t* sr1 = supp + ((size_t)b * RROWS + r1) * NWSTRIDE;
    uint64_t* sr2 = supp + ((size_t)b * RROWS + r2) * NWSTRIDE;
    if (lane < 24) {
        uint64_t k0 = keep0, k1 = keep1, k2 = keep2;
        if (quad == 3 && lane >= 22) { k0 = 0; k1 = 0; k2 = 0; }   // pad words 94,95
        sr0[wlo + lane] = k0;
        sr1[wlo + lane] = k1;
        sr2[wlo + lane] = k2;
    }
}

// ---------------- K6b: sequential walk; 6-buffer pinned prefetch; UNIFORM loads ----------
#define ISSUE(BUF, GRP) do {                                                               \
    int _g = (GRP); if (_g > NGROUPS - 1) _g = NGROUPS - 1;                                \
    int _jb = _g << 3;                                                                     \
    const ulonglong2* _p = (const ulonglong2*)(sbase + (size_t)_jb * NWSTRIDE) + lclamp;   \
    BUF##0 = _p[0];   BUF##1 = _p[48];  BUF##2 = _p[96];  BUF##3 = _p[144];                \
    BUF##4 = _p[192]; BUF##5 = _p[240]; BUF##6 = _p[288]; BUF##7 = _p[336];                \
    __builtin_amdgcn_sched_barrier(0);  /* pin: loads stay issued HERE, not sunk */        \
} while (0)

#define ROWP(RD, JB, R) {                                                                  \
    if (((curw >> (((JB) & 63) + (R))) & 1ull) != 0ull) {                                  \
        if (lane == 0) idxb[t] = (uint32_t)((JB) + (R));                                   \
        v0 &= ~RD.x; v1 &= ~RD.y;                                                          \
        int _w = ((JB) + (R)) >> 6;                                                        \
        uint64_t _sw = (uint64_t)__shfl((long long)((_w & 1) ? RD.y : RD.x), _w >> 1);     \
        curw &= ~_sw;                                                                      \
        ++t;                                                                               \
        if (t >= POST) goto walk_done;                                                     \
    }                                                                                      \
}

#define PROC(BUF, GRP) do {                                                                \
    int _jb2 = (GRP) << 3;                                                                 \
    if ((_jb2 & 63) == 0) {                                                                \
        int _wi = _jb2 >> 6;                                                               \
        uint64_t _c0 = (uint64_t)__shfl((long long)v0, _wi >> 1);                          \
        uint64_t _c1 = (uint64_t)__shfl((long long)v1, _wi >> 1);                          \
        curw = (_wi & 1) ? _c1 : _c0;                                                      \
    }                                                                                      \
    ROWP(BUF##0, _jb2, 0); ROWP(BUF##1, _jb2, 1); ROWP(BUF##2, _jb2, 2); ROWP(BUF##3, _jb2, 3); \
    ROWP(BUF##4, _jb2, 4); ROWP(BUF##5, _jb2, 5); ROWP(BUF##6, _jb2, 6); ROWP(BUF##7, _jb2, 7); \
} while (0)

__global__ __launch_bounds__(64, 1) void k_walk(const uint64_t* __restrict__ supp,
                                                uint32_t* __restrict__ flags,
                                                uint32_t* __restrict__ tsave,
                                                uint64_t* __restrict__ aliveSv,
                                                uint32_t* __restrict__ idxAll) {
    int b = blockIdx.x;
    int lane = threadIdx.x;
    int lclamp = (lane < 48) ? lane : 47;
    uint32_t* idxb = idxAll + b * POST;
    const uint64_t* sbase = supp + (size_t)b * RROWS * NWSTRIDE;
    uint64_t v0, v1;
    if (lane < 46)       { v0 = ~0ull; v1 = ~0ull; }
    else if (lane == 46) { v0 = ~0ull; v1 = (1ull << 48) - 1ull; }
    else                 { v0 = 0ull;  v1 = 0ull; }
    uint64_t curw = 0;
    int t = 0;
    int flag = 0;
    ulonglong2 A0,A1,A2,A3,A4,A5,A6,A7;
    ulonglong2 B0,B1,B2,B3,B4,B5,B6,B7;
    ulonglong2 C0,C1,C2,C3,C4,C5,C6,C7;
    ulonglong2 D0,D1,D2,D3,D4,D5,D6,D7;
    ulonglong2 E0,E1,E2,E3,E4,E5,E6,E7;
    ulonglong2 F0,F1,F2,F3,F4,F5,F6,F7;
    ISSUE(A, 0); ISSUE(B, 1); ISSUE(C, 2); ISSUE(D, 3); ISSUE(E, 4); ISSUE(F, 5);
    // NGROUPS = 48 = 8 * 6: clean 6-buffer rounds, no tail.
    for (int g = 0; g < NGROUPS; g += 6) {
        PROC(A, g);     ISSUE(A, g + 6);
        PROC(B, g + 1); ISSUE(B, g + 7);
        PROC(C, g + 2); ISSUE(C, g + 8);
        PROC(D, g + 3); ISSUE(D, g + 9);
        PROC(E, g + 4); ISSUE(E, g + 10);
        PROC(F, g + 5); ISSUE(F, g + 11);
    }
    {
        unsigned long long anyAlive = __ballot((v0 | v1) != 0ull);
        if (anyAlive == 0ull) {
            if (lane == 0) for (int tt = t; tt < POST; ++tt) idxb[tt] = 0u;
        } else {
            if (2 * lane < NWORDS)     aliveSv[b * NWORDS + 2 * lane] = v0;
            if (2 * lane + 1 < NWORDS) aliveSv[b * NWORDS + 2 * lane + 1] = v1;
            if (lane == 0) tsave[b] = (uint32_t)t;
            flag = 1;
        }
    }
walk_done:
    if (lane == 0) flags[b] = (uint32_t)flag;
}

// ---------------- K6c: rare exact fallback; records indices; early-exit flag==0 ----------
__global__ __launch_bounds__(512) void k_resume(const float4* __restrict__ boxes,
                                                const uint32_t* __restrict__ flags,
                                                const uint32_t* __restrict__ tsave,
                                                const uint64_t* __restrict__ aliveSv,
                                                uint32_t* __restrict__ idxAll) {
    int b = blockIdx.x;
    if (flags[b] == 0) return;
    __shared__ uint64_t alive[NWORDS];
    __shared__ uint32_t sCur;
    int tid = threadIdx.x;
    const float4* bb = boxes + b * PRE;
    uint32_t* idxb = idxAll + b * POST;
    if (tid < NWORDS) alive[tid] = aliveSv[b * NWORDS + tid];
    __syncthreads();
    int t0 = (int)tsave[b];
    for (int t = t0; t < POST; ++t) {
        if (tid == 0) sCur = 0xFFFFFFFFu;
        __syncthreads();
        if (tid < NWORDS) {
            uint64_t wd = alive[tid];
            if (wd) atomicMin(&sCur, (uint32_t)(tid * 64 + (__ffsll((unsigned long long)wd) - 1)));
        }
        __syncthreads();
        uint32_t cur = sCur;
        uint32_t e = (cur < (uint32_t)PRE) ? cur : 0u;
        if (tid == 0) {
            idxb[t] = e;
            if (cur < (uint32_t)PRE)
                atomicAnd(&alive[cur >> 6], ~(1ull << (cur & 63)));
        }
        if (cur < (uint32_t)PRE) {
            float4 bc = bb[e];
            float areaC = __fmul_rn(__fadd_rn(__fsub_rn(bc.z, bc.x), 1.f),
                                    __fadd_rn(__fsub_rn(bc.w, bc.y), 1.f));
            for (uint32_t j = cur + 1 + tid; j < (uint32_t)PRE; j += 512) {
                uint64_t wd = alive[j >> 6];
                if ((wd >> (j & 63)) & 1ull) {
                    float4 bj = bb[j];
                    float areaJ = __fmul_rn(__fadd_rn(__fsub_rn(bj.z, bj.x), 1.f),
                                            __fadd_rn(__fsub_rn(bj.w, bj.y), 1.f));
                    if (iou_sup(bc, areaC, bj, areaJ))
                        atomicAnd(&alive[j >> 6], ~(1ull << (j & 63)));
                }
            }
        }
        __syncthreads();
    }
}

// ---------------- K7: gather emitted indices -> output boxes + scores ----------------
__global__ __launch_bounds__(256) void k_out(const float4* __restrict__ boxes,
                                             const float* __restrict__ scores,
                                             const uint32_t* __restrict__ idxAll,
                                             float* __restrict__ out) {
    int g = blockIdx.x * 256 + threadIdx.x;
    if (g >= NBATCH * POST) return;
    int b = g / POST;
    uint32_t i = idxAll[g];
    if (i >= (uint32_t)PRE) i = 0;
    float4 bc = boxes[b * PRE + i];
    size_t ob = (size_t)g * 4;
    out[ob + 0] = bc.x; out[ob + 1] = bc.y;
    out[ob + 2] = bc.z; out[ob + 3] = bc.w;
    out[(size_t)NBATCH * POST * 4 + g] = scores[b * PRE + i];
}

extern "C" void kernel_launch(void* const* d_in, const int* in_sizes, int n_in,
                              void* d_out, int out_size, void* d_ws, size_t ws_size,
                              hipStream_t stream) {
    (void)in_sizes; (void)n_in; (void)out_size; (void)ws_size;
    const float* lab = (const float*)d_in[0];
    const float* reg = (const float*)d_in[1];
    float* out = (float*)d_out;
    char* ws = (char*)d_ws;

    // workspace layout (bytes)
    uint32_t* ghist  = (uint32_t*)(ws + 0);          // 16*8192*4 = 524288
    uint32_t* cnt    = (uint32_t*)(ws + 524288);     // 64
    uint32_t* thr    = (uint32_t*)(ws + 524352);     // 64
    uint64_t* cand   = (uint64_t*)(ws + 524416);     // -> 1572992
    float4*   boxes  = (float4*)  (ws + 1572992);    // -> 3108992
    float*    scores = (float*)   (ws + 3108992);    // -> 3492992
    uint64_t* supp   = (uint64_t*)(ws + 3492992);    // 16*384*96*8 = 4718592 -> 8211584
    uint32_t* flags  = (uint32_t*)(ws + 8211584);    // 64
    uint32_t* tsave  = (uint32_t*)(ws + 8211648);    // 64
    uint64_t* aliveS = (uint64_t*)(ws + 8211712);    // -> 8223744
    uint32_t* idx    = (uint32_t*)(ws + 8223744);    // -> 8242944
    uint32_t* keys   = (uint32_t*)(ws + 8242944);    // -> 27117312
    uint64_t* cand2  = (uint64_t*)(ws + 27117312);   // -> 28165888

    k_zero       <<<129, 256, 0, stream>>>((uint4*)ghist, cnt);
    k_hist       <<<512, 256, 0, stream>>>(lab, reg, ghist, keys);
    k_thresh     <<<NBATCH, 256, 0, stream>>>(ghist, thr);
    k_compact    <<<2048, 256, 0, stream>>>(keys, thr, cnt, cand);
    k_sortA      <<<NBATCH * 8, 512, 0, stream>>>(cnt, cand);
    k_merge      <<<NBATCH * CAPN / 256, 256, 0, stream>>>(cand, cand2, 10);  // 1024 -> 2048
    k_merge      <<<NBATCH * CAPN / 256, 256, 0, stream>>>(cand2, cand, 11);  // 2048 -> 4096
    k_mergegather<<<(NBATCH * PRE + 255) / 256, 256, 0, stream>>>(cand, lab, reg, boxes, scores);
    k_iou        <<<NBATCH * 64, 512, 0, stream>>>(boxes, supp);
    k_walk       <<<NBATCH, 64, 0, stream>>>(supp, flags, tsave, aliveS, idx);
    k_resume     <<<NBATCH, 512, 0, stream>>>(boxes, flags, tsave, aliveS, idx);
    k_out        <<<(NBATCH * POST + 255) / 256, 256, 0, stream>>>(boxes, scores, idx, out);
}